// Round 1
// 124.699 us; speedup vs baseline: 1.0671x; 1.0671x over previous
//
#include <hip/hip_runtime.h>
#include <stdint.h>

// DETR post-process: per batch n of 256, top-300 of sigmoid(logits[n]) (80000
// elems), output [label, score, scaled box] per selected query.
//
// Ordering: jax top_k = score desc, tie -> lowest index. sigmoid is strictly
// monotonic, so we rank on 64-bit key (ord(logit)<<32 | ~index): descending
// key order == (score desc, index asc) exactly.
//
// R5 structure: one 1024-thread block per batch, ONE streaming scan.
//   Fast path: compact all logits >= 2.4f straight into LDS (~650 expected
//   for N(0,1) data; bounds [300, 2048] are 14+ sigma safe). Verified
//   in-kernel: if cnt outside [TOPK, CAP], run a full radix-select fallback
//   (correct for arbitrary data, never taken for the bench input).
//
//   NEW in R5: rank phase is no longer O(cnt^2) broadcast-read-by-count
//   (~7200 serialized ds_read_b64 per CU ~= 15-20 us). Instead: monotone
//   2048-bin histogram on (ord - baseord) >> 12, suffix-scan for per-bin
//   start rank, scatter into bin-ordered slots, then exact within-bin tie
//   count (bins hold ~1-4 candidates for bench data; arbitrary data merely
//   degrades speed, never correctness).
//
// Hard-learned rules: NO per-thread arrays with runtime indexing (R2/R3:
// scratch spill, WRITE_SIZE 49/161 MB). All load indices compile-time affine.

#define TOPK 300
#define NCLS 80
#define NQ 1000
#define QK (NQ * NCLS)   // 80000
#define NB 2048
#define CAP 2048
#define THREADS 1024
#define LAST_VALID 544   // j=19: 4*t + 4096*19 < 80000  <=>  t < 544
#define T0F 2.4f         // fixed fast-path threshold (z-score)
#define RSH 12           // rank-bin shift: bin = (ord - base) >> RSH

typedef unsigned long long u64;

__device__ __forceinline__ uint32_t ordf(float f) {
  uint32_t u = __float_as_uint(f);
  return (u & 0x80000000u) ? ~u : (u | 0x80000000u);  // monotonic float->uint
}
__device__ __forceinline__ float unordf(uint32_t o) {
  uint32_t u = (o & 0x80000000u) ? (o & 0x7fffffffu) : ~o;
  return __uint_as_float(u);
}

__global__ __launch_bounds__(THREADS) void detr_post_kernel(
    const float* __restrict__ logits, const float* __restrict__ boxes,
    const int* __restrict__ osz, float* __restrict__ out) {
  __shared__ u64 buf[CAP];       // 16 KB: compaction buffer (both paths)
  __shared__ u64 smem64[4096];   // 32 KB: fallback hist4 | {buf2, rh, rcur}
  __shared__ uint32_t histf[NB]; // 8 KB: fallback prefix only
  __shared__ uint32_t sh_sel[3];
  __shared__ uint32_t sh_cnt;

  // aliases into smem64 (fallback hist4 is dead before the rank phase)
  uint32_t* const hist4 = (uint32_t*)smem64;        // 8192 u32 (fallback)
  u64* const buf2 = smem64;                         // 2048 u64 (rank scatter)
  uint32_t* const rh = (uint32_t*)(smem64 + 2048);  // 2048 u32 (bin counts)
  uint32_t* const rcur = (uint32_t*)(smem64 + 3072);// 2048 u32 (scan/cursor)

  const int n = blockIdx.x;
  const int t = threadIdx.x;
  const float* lg = logits + (size_t)n * QK;

  // ---- fast path: single streaming scan, compact x >= T0F into LDS.
  if (t == 0) sh_cnt = 0;
  __syncthreads();

#pragma unroll 5
  for (int j = 0; j < 19; ++j) {
    const int i = 4 * t + 4096 * j;
    const float4 v = *(const float4*)(lg + i);
    if (v.x >= T0F) {
      const uint32_t p = atomicAdd(&sh_cnt, 1u);
      if (p < CAP) buf[p] = ((u64)ordf(v.x) << 32) | (u64)(~(uint32_t)(i + 0));
    }
    if (v.y >= T0F) {
      const uint32_t p = atomicAdd(&sh_cnt, 1u);
      if (p < CAP) buf[p] = ((u64)ordf(v.y) << 32) | (u64)(~(uint32_t)(i + 1));
    }
    if (v.z >= T0F) {
      const uint32_t p = atomicAdd(&sh_cnt, 1u);
      if (p < CAP) buf[p] = ((u64)ordf(v.z) << 32) | (u64)(~(uint32_t)(i + 2));
    }
    if (v.w >= T0F) {
      const uint32_t p = atomicAdd(&sh_cnt, 1u);
      if (p < CAP) buf[p] = ((u64)ordf(v.w) << 32) | (u64)(~(uint32_t)(i + 3));
    }
  }
  if (t < LAST_VALID) {
    const int i = 4 * t + 4096 * 19;
    const float4 v = *(const float4*)(lg + i);
    if (v.x >= T0F) {
      const uint32_t p = atomicAdd(&sh_cnt, 1u);
      if (p < CAP) buf[p] = ((u64)ordf(v.x) << 32) | (u64)(~(uint32_t)(i + 0));
    }
    if (v.y >= T0F) {
      const uint32_t p = atomicAdd(&sh_cnt, 1u);
      if (p < CAP) buf[p] = ((u64)ordf(v.y) << 32) | (u64)(~(uint32_t)(i + 1));
    }
    if (v.z >= T0F) {
      const uint32_t p = atomicAdd(&sh_cnt, 1u);
      if (p < CAP) buf[p] = ((u64)ordf(v.z) << 32) | (u64)(~(uint32_t)(i + 2));
    }
    if (v.w >= T0F) {
      const uint32_t p = atomicAdd(&sh_cnt, 1u);
      if (p < CAP) buf[p] = ((u64)ordf(v.w) << 32) | (u64)(~(uint32_t)(i + 3));
    }
  }
  __syncthreads();

  uint32_t cnt = sh_cnt;
  const bool fast_ok = (cnt >= TOPK && cnt <= CAP);  // block-uniform
  uint32_t baseord = ordf(T0F);                      // min possible cand ord

  if (!fast_ok) {
    // ---- fallback: full radix select on ord(logit), then recompact.
    // Correct for arbitrary inputs; never taken for the bench distribution.
    uint32_t T = 0, S_above = 0, Krem = TOPK;
    int prev_shift = 32;
    const uint32_t sub = (uint32_t)(t & 3);
    const int shifts[3] = {21, 10, 0};
    const int nbns[3] = {2048, 2048, 1024};

    for (int lvl = 0; lvl < 3; ++lvl) {
      const int sh = shifts[lvl];
      const uint32_t nb = (uint32_t)nbns[lvl];

      for (int b = t; b < NB * 4; b += THREADS) hist4[b] = 0;
      __syncthreads();
      for (int j = 0; j < 20; ++j) {
        if (j == 19 && t >= LAST_VALID) break;
        const int i = 4 * t + 4096 * j;
        const float4 v = *(const float4*)(lg + i);
        const float vs[4] = {v.x, v.y, v.z, v.w};
        for (int c = 0; c < 4; ++c) {
          const uint32_t u = ordf(vs[c]);
          if (lvl == 0 || (u >> prev_shift) == (T >> prev_shift))
            atomicAdd(&hist4[(((u >> sh) & (nb - 1)) << 2) | sub], 1u);
        }
      }
      __syncthreads();

      for (uint32_t b = t; b < nb; b += (uint32_t)THREADS) {
        const uint32_t i4 = b << 2;
        histf[b] = hist4[i4] + hist4[i4 + 1] + hist4[i4 + 2] + hist4[i4 + 3];
      }
      __syncthreads();

      for (uint32_t off = 1; off < nb; off <<= 1) {
        uint32_t a0 = histf[t] + ((t + off < nb) ? histf[t + off] : 0u);
        uint32_t a1 = 0;
        if (nb > (uint32_t)THREADS) {
          const uint32_t i1 = (uint32_t)t + THREADS;
          a1 = histf[i1] + ((i1 + off < nb) ? histf[i1 + off] : 0u);
        }
        __syncthreads();
        histf[t] = a0;
        if (nb > (uint32_t)THREADS) histf[(uint32_t)t + THREADS] = a1;
        __syncthreads();
      }

      for (uint32_t b = t; b < nb; b += (uint32_t)THREADS) {
        const uint32_t s = histf[b];
        const uint32_t sn = (b + 1 < nb) ? histf[b + 1] : 0u;
        if (s >= Krem && sn < Krem) {
          sh_sel[0] = b;
          sh_sel[1] = sn;
          sh_sel[2] = s;
        }
      }
      __syncthreads();
      const uint32_t bsel = sh_sel[0], above = sh_sel[1], candL = sh_sel[2];
      __syncthreads();

      T |= bsel << sh;
      if (S_above + candL <= CAP || lvl == 2) break;
      S_above += above;
      Krem -= above;
      prev_shift = sh;
    }

    // recompact with the radix-derived ordered threshold
    if (t == 0) sh_cnt = 0;
    __syncthreads();
    for (int j = 0; j < 20; ++j) {
      if (j == 19 && t >= LAST_VALID) break;
      const int i = 4 * t + 4096 * j;
      const float4 v = *(const float4*)(lg + i);
      const float vs[4] = {v.x, v.y, v.z, v.w};
      for (int c = 0; c < 4; ++c) {
        const uint32_t u = ordf(vs[c]);
        if (u >= T) {
          const uint32_t p = atomicAdd(&sh_cnt, 1u);
          if (p < CAP) buf[p] = ((u64)u << 32) | (u64)(~(uint32_t)(i + c));
        }
      }
    }
    __syncthreads();
    cnt = sh_cnt < CAP ? sh_cnt : CAP;
    baseord = T;  // all compacted keys have ord >= T
  }

  // ---- rank via monotone 2048-bin histogram on (ord - baseord) >> RSH.
  // bin(a) > bin(b)  =>  a > b  (strict), so
  // rank(key) = (#keys in higher bins) + (#same-bin keys > key)  -- exact.
  for (int b = t; b < NB; b += THREADS) rh[b] = 0;
  __syncthreads();

  // each thread owns <= 2 candidates (cnt <= 2048 = 2*THREADS)
  const u64 k0 = ((uint32_t)t < cnt) ? buf[t] : 0ULL;
  const u64 k1 = ((uint32_t)(t + THREADS) < cnt) ? buf[t + THREADS] : 0ULL;
  uint32_t b0 = 0, b1 = 0;
  if ((uint32_t)t < cnt) {
    b0 = ((uint32_t)(k0 >> 32) - baseord) >> RSH;
    if (b0 > NB - 1u) b0 = NB - 1u;
    atomicAdd(&rh[b0], 1u);
  }
  if ((uint32_t)(t + THREADS) < cnt) {
    b1 = ((uint32_t)(k1 >> 32) - baseord) >> RSH;
    if (b1 > NB - 1u) b1 = NB - 1u;
    atomicAdd(&rh[b1], 1u);
  }
  __syncthreads();

  // inclusive suffix-scan: rcur[b] = sum_{b' >= b} rh[b']
  for (int b = t; b < NB; b += THREADS) rcur[b] = rh[b];
  __syncthreads();
  for (uint32_t off = 1; off < NB; off <<= 1) {
    const uint32_t i1 = (uint32_t)t + THREADS;
    const uint32_t a0 =
        rcur[t] + (((uint32_t)t + off < NB) ? rcur[t + off] : 0u);
    const uint32_t a1 = rcur[i1] + ((i1 + off < NB) ? rcur[i1 + off] : 0u);
    __syncthreads();
    rcur[t] = a0;
    rcur[i1] = a1;
    __syncthreads();
  }
  // exclusive-from-top start cursor: start[b] = sum_{b' > b} rh[b']
  for (int b = t; b < NB; b += THREADS) rcur[b] -= rh[b];
  __syncthreads();

  // scatter candidates into bin-ordered slots of buf2
  if ((uint32_t)t < cnt) {
    const uint32_t s = atomicAdd(&rcur[b0], 1u);
    buf2[s] = k0;
  }
  if ((uint32_t)(t + THREADS) < cnt) {
    const uint32_t s = atomicAdd(&rcur[b1], 1u);
    buf2[s] = k1;
  }
  __syncthreads();
  // now rcur[b] = start[b] + rh[b] = segment end for bin b

  const float s0 = (float)osz[0];
  const float s1 = (float)osz[1];

  // within-bin exact rank + emit (bin segments are ~1-4 keys for bench data)
  if ((uint32_t)t < cnt) {
    const uint32_t end = rcur[b0];
    const uint32_t beg = end - rh[b0];
    uint32_t rank = beg;
    for (uint32_t q = beg; q < end; ++q) rank += (uint32_t)(buf2[q] > k0);
    if (rank < TOPK) {
      const uint32_t u = (uint32_t)(k0 >> 32);
      const uint32_t idx = ~(uint32_t)(k0 & 0xffffffffu);
      const float lgv = unordf(u);
      const float score = 1.0f / (1.0f + expf(-lgv));
      const uint32_t q = idx / NCLS;
      const uint32_t lab = idx - q * NCLS;
      const float* bp = boxes + ((size_t)n * NQ + q) * 4;
      const float cx = bp[0], cy = bp[1], w = bp[2], h = bp[3];
      float* op = out + ((size_t)n * TOPK + rank) * 6;
      op[0] = (float)lab;
      op[1] = score;
      op[2] = (cx - 0.5f * w) * s1;
      op[3] = (cy - 0.5f * h) * s0;
      op[4] = w * s1;
      op[5] = h * s0;
    }
  }
  if ((uint32_t)(t + THREADS) < cnt) {
    const uint32_t end = rcur[b1];
    const uint32_t beg = end - rh[b1];
    uint32_t rank = beg;
    for (uint32_t q = beg; q < end; ++q) rank += (uint32_t)(buf2[q] > k1);
    if (rank < TOPK) {
      const uint32_t u = (uint32_t)(k1 >> 32);
      const uint32_t idx = ~(uint32_t)(k1 & 0xffffffffu);
      const float lgv = unordf(u);
      const float score = 1.0f / (1.0f + expf(-lgv));
      const uint32_t q = idx / NCLS;
      const uint32_t lab = idx - q * NCLS;
      const float* bp = boxes + ((size_t)n * NQ + q) * 4;
      const float cx = bp[0], cy = bp[1], w = bp[2], h = bp[3];
      float* op = out + ((size_t)n * TOPK + rank) * 6;
      op[0] = (float)lab;
      op[1] = score;
      op[2] = (cx - 0.5f * w) * s1;
      op[3] = (cy - 0.5f * h) * s0;
      op[4] = w * s1;
      op[5] = h * s0;
    }
  }
}

extern "C" void kernel_launch(void* const* d_in, const int* in_sizes, int n_in,
                              void* d_out, int out_size, void* d_ws, size_t ws_size,
                              hipStream_t stream) {
  const float* logits = (const float*)d_in[0];
  const float* boxes = (const float*)d_in[1];
  const int* osz = (const int*)d_in[2];
  float* out = (float*)d_out;
  const int nbatch = in_sizes[0] / QK;  // 256
  detr_post_kernel<<<nbatch, THREADS, 0, stream>>>(logits, boxes, osz, out);
}

// Round 2
// 124.413 us; speedup vs baseline: 1.0696x; 1.0023x over previous
//
#include <hip/hip_runtime.h>
#include <stdint.h>

// DETR post-process: per batch n of 256, top-300 of sigmoid(logits[n]) (80000
// elems), output [label, score, scaled box] per selected query.
//
// Ordering: jax top_k = score desc, tie -> lowest index. sigmoid is strictly
// monotonic, so we rank on 64-bit key (ord(logit)<<32 | ~index): descending
// key order == (score desc, index asc) exactly.
//
// R6 structure: one 1024-thread block per batch, ONE streaming scan.
//   Fast path: compact all logits >= 2.4f straight into LDS (~650 expected
//   for N(0,1) data; bounds [300, 2048] are 14+ sigma safe). Verified
//   in-kernel: if cnt outside [TOPK, CAP], run a full radix-select fallback
//   (correct for arbitrary data, never taken for the bench input).
//
//   Rank: monotone 512-bin histogram on (ord - baseord) >> 14, then a
//   SINGLE-WAVE shfl suffix-scan (lane owns 8 bins, 6 shfl_down steps, no
//   barriers), scatter into bin-ordered slots, exact within-bin tie count.
//   R5's 2048-bin all-wave log-step scan cost 22 __syncthreads at 16 waves;
//   whole kernel now has ~6 barriers. Arbitrary data only degrades speed
//   (bigger tie segments), never correctness.
//
// Hard-learned rules: NO per-thread arrays with runtime indexing (R2/R3:
// scratch spill, WRITE_SIZE 49/161 MB). All load indices compile-time affine.

#define TOPK 300
#define NCLS 80
#define NQ 1000
#define QK (NQ * NCLS)   // 80000
#define NB 2048          // fallback radix bins
#define CAP 2048
#define THREADS 1024
#define LAST_VALID 544   // j=19: 4*t + 4096*19 < 80000  <=>  t < 544
#define T0F 2.4f         // fixed fast-path threshold (z-score)
#define RNB 512          // rank bins
#define RSH 14           // rank-bin shift: bin = (ord - base) >> RSH

typedef unsigned long long u64;

__device__ __forceinline__ uint32_t ordf(float f) {
  uint32_t u = __float_as_uint(f);
  return (u & 0x80000000u) ? ~u : (u | 0x80000000u);  // monotonic float->uint
}
__device__ __forceinline__ float unordf(uint32_t o) {
  uint32_t u = (o & 0x80000000u) ? (o & 0x7fffffffu) : ~o;
  return __uint_as_float(u);
}

__device__ __forceinline__ void rank_emit(
    const u64 key, const uint32_t bin, const uint32_t* rcur,
    const uint32_t* rh, const u64* buf2, const float* boxes, float* out,
    const int n, const float s0, const float s1) {
  const uint32_t end = rcur[bin];          // start[bin] + count[bin]
  const uint32_t beg = end - rh[bin];
  uint32_t rank = beg;                     // #keys in strictly-higher bins
  for (uint32_t q = beg; q < end; ++q) rank += (uint32_t)(buf2[q] > key);
  if (rank < TOPK) {
    const uint32_t u = (uint32_t)(key >> 32);
    const uint32_t idx = ~(uint32_t)(key & 0xffffffffu);
    const float lgv = unordf(u);
    const float score = 1.0f / (1.0f + expf(-lgv));
    const uint32_t q = idx / NCLS;
    const uint32_t lab = idx - q * NCLS;
    const float4 b4 = *(const float4*)(boxes + ((size_t)n * NQ + q) * 4);
    float* op = out + ((size_t)n * TOPK + rank) * 6;  // 8-byte aligned
    float2* op2 = (float2*)op;
    op2[0] = make_float2((float)lab, score);
    op2[1] = make_float2((b4.x - 0.5f * b4.z) * s1, (b4.y - 0.5f * b4.w) * s0);
    op2[2] = make_float2(b4.z * s1, b4.w * s0);
  }
}

__global__ __launch_bounds__(THREADS) void detr_post_kernel(
    const float* __restrict__ logits, const float* __restrict__ boxes,
    const int* __restrict__ osz, float* __restrict__ out) {
  __shared__ u64 buf[CAP];       // 16 KB: compaction buffer (both paths)
  __shared__ u64 smem64[4096];   // 32 KB: fallback hist4 | {buf2, rh, rcur}
  __shared__ uint32_t histf[NB]; // 8 KB: fallback prefix only
  __shared__ uint32_t sh_sel[3];
  __shared__ uint32_t sh_cnt;

  // aliases into smem64 (fallback hist4 is dead before the rank phase)
  uint32_t* const hist4 = (uint32_t*)smem64;        // 8192 u32 (fallback)
  u64* const buf2 = smem64;                         // 2048 u64 (rank scatter)
  uint32_t* const rh = (uint32_t*)(smem64 + 2048);  // 512 u32 (bin counts)
  uint32_t* const rcur = (uint32_t*)(smem64 + 2304);// 512 u32 (start/cursor)

  const int n = blockIdx.x;
  const int t = threadIdx.x;
  const float* lg = logits + (size_t)n * QK;

  // ---- init: scan counter + rank-bin counts (one barrier covers both)
  if (t == 0) sh_cnt = 0;
  if (t < RNB) rh[t] = 0;
  __syncthreads();

  // ---- fast path: single streaming scan, compact x >= T0F into LDS.
#pragma unroll 5
  for (int j = 0; j < 19; ++j) {
    const int i = 4 * t + 4096 * j;
    const float4 v = *(const float4*)(lg + i);
    if (v.x >= T0F) {
      const uint32_t p = atomicAdd(&sh_cnt, 1u);
      if (p < CAP) buf[p] = ((u64)ordf(v.x) << 32) | (u64)(~(uint32_t)(i + 0));
    }
    if (v.y >= T0F) {
      const uint32_t p = atomicAdd(&sh_cnt, 1u);
      if (p < CAP) buf[p] = ((u64)ordf(v.y) << 32) | (u64)(~(uint32_t)(i + 1));
    }
    if (v.z >= T0F) {
      const uint32_t p = atomicAdd(&sh_cnt, 1u);
      if (p < CAP) buf[p] = ((u64)ordf(v.z) << 32) | (u64)(~(uint32_t)(i + 2));
    }
    if (v.w >= T0F) {
      const uint32_t p = atomicAdd(&sh_cnt, 1u);
      if (p < CAP) buf[p] = ((u64)ordf(v.w) << 32) | (u64)(~(uint32_t)(i + 3));
    }
  }
  if (t < LAST_VALID) {
    const int i = 4 * t + 4096 * 19;
    const float4 v = *(const float4*)(lg + i);
    if (v.x >= T0F) {
      const uint32_t p = atomicAdd(&sh_cnt, 1u);
      if (p < CAP) buf[p] = ((u64)ordf(v.x) << 32) | (u64)(~(uint32_t)(i + 0));
    }
    if (v.y >= T0F) {
      const uint32_t p = atomicAdd(&sh_cnt, 1u);
      if (p < CAP) buf[p] = ((u64)ordf(v.y) << 32) | (u64)(~(uint32_t)(i + 1));
    }
    if (v.z >= T0F) {
      const uint32_t p = atomicAdd(&sh_cnt, 1u);
      if (p < CAP) buf[p] = ((u64)ordf(v.z) << 32) | (u64)(~(uint32_t)(i + 2));
    }
    if (v.w >= T0F) {
      const uint32_t p = atomicAdd(&sh_cnt, 1u);
      if (p < CAP) buf[p] = ((u64)ordf(v.w) << 32) | (u64)(~(uint32_t)(i + 3));
    }
  }
  __syncthreads();

  uint32_t cnt = sh_cnt;
  const bool fast_ok = (cnt >= TOPK && cnt <= CAP);  // block-uniform
  uint32_t baseord = ordf(T0F);                      // min possible cand ord

  if (!fast_ok) {
    // ---- fallback: full radix select on ord(logit), then recompact.
    // Correct for arbitrary inputs; never taken for the bench distribution.
    uint32_t T = 0, S_above = 0, Krem = TOPK;
    int prev_shift = 32;
    const uint32_t sub = (uint32_t)(t & 3);
    const int shifts[3] = {21, 10, 0};
    const int nbns[3] = {2048, 2048, 1024};

    for (int lvl = 0; lvl < 3; ++lvl) {
      const int sh = shifts[lvl];
      const uint32_t nb = (uint32_t)nbns[lvl];

      for (int b = t; b < NB * 4; b += THREADS) hist4[b] = 0;
      __syncthreads();
      for (int j = 0; j < 20; ++j) {
        if (j == 19 && t >= LAST_VALID) break;
        const int i = 4 * t + 4096 * j;
        const float4 v = *(const float4*)(lg + i);
        const float vs[4] = {v.x, v.y, v.z, v.w};
        for (int c = 0; c < 4; ++c) {
          const uint32_t u = ordf(vs[c]);
          if (lvl == 0 || (u >> prev_shift) == (T >> prev_shift))
            atomicAdd(&hist4[(((u >> sh) & (nb - 1)) << 2) | sub], 1u);
        }
      }
      __syncthreads();

      for (uint32_t b = t; b < nb; b += (uint32_t)THREADS) {
        const uint32_t i4 = b << 2;
        histf[b] = hist4[i4] + hist4[i4 + 1] + hist4[i4 + 2] + hist4[i4 + 3];
      }
      __syncthreads();

      for (uint32_t off = 1; off < nb; off <<= 1) {
        uint32_t a0 = histf[t] + ((t + off < nb) ? histf[t + off] : 0u);
        uint32_t a1 = 0;
        if (nb > (uint32_t)THREADS) {
          const uint32_t i1 = (uint32_t)t + THREADS;
          a1 = histf[i1] + ((i1 + off < nb) ? histf[i1 + off] : 0u);
        }
        __syncthreads();
        histf[t] = a0;
        if (nb > (uint32_t)THREADS) histf[(uint32_t)t + THREADS] = a1;
        __syncthreads();
      }

      for (uint32_t b = t; b < nb; b += (uint32_t)THREADS) {
        const uint32_t s = histf[b];
        const uint32_t sn = (b + 1 < nb) ? histf[b + 1] : 0u;
        if (s >= Krem && sn < Krem) {
          sh_sel[0] = b;
          sh_sel[1] = sn;
          sh_sel[2] = s;
        }
      }
      __syncthreads();
      const uint32_t bsel = sh_sel[0], above = sh_sel[1], candL = sh_sel[2];
      __syncthreads();

      T |= bsel << sh;
      if (S_above + candL <= CAP || lvl == 2) break;
      S_above += above;
      Krem -= above;
      prev_shift = sh;
    }

    // recompact with the radix-derived ordered threshold; re-zero rank bins
    // (fallback hist4 aliased them)
    if (t == 0) sh_cnt = 0;
    __syncthreads();
    if (t < RNB) rh[t] = 0;
    for (int j = 0; j < 20; ++j) {
      if (j == 19 && t >= LAST_VALID) break;
      const int i = 4 * t + 4096 * j;
      const float4 v = *(const float4*)(lg + i);
      const float vs[4] = {v.x, v.y, v.z, v.w};
      for (int c = 0; c < 4; ++c) {
        const uint32_t u = ordf(vs[c]);
        if (u >= T) {
          const uint32_t p = atomicAdd(&sh_cnt, 1u);
          if (p < CAP) buf[p] = ((u64)u << 32) | (u64)(~(uint32_t)(i + c));
        }
      }
    }
    __syncthreads();
    cnt = sh_cnt < CAP ? sh_cnt : CAP;
    baseord = T;  // all compacted keys have ord >= T
  }

  // ---- rank via monotone 512-bin histogram on (ord - baseord) >> RSH.
  // bin(a) > bin(b)  =>  a > b  (strict), so
  // rank(key) = (#keys in higher bins) + (#same-bin keys > key)  -- exact.
  // each thread owns <= 2 candidates (cnt <= 2048 = 2*THREADS)
  const u64 k0 = ((uint32_t)t < cnt) ? buf[t] : 0ULL;
  const u64 k1 = ((uint32_t)(t + THREADS) < cnt) ? buf[t + THREADS] : 0ULL;
  uint32_t b0 = 0, b1 = 0;
  if ((uint32_t)t < cnt) {
    b0 = ((uint32_t)(k0 >> 32) - baseord) >> RSH;
    if (b0 > RNB - 1u) b0 = RNB - 1u;
    atomicAdd(&rh[b0], 1u);
  }
  if ((uint32_t)(t + THREADS) < cnt) {
    b1 = ((uint32_t)(k1 >> 32) - baseord) >> RSH;
    if (b1 > RNB - 1u) b1 = RNB - 1u;
    atomicAdd(&rh[b1], 1u);
  }
  __syncthreads();

  // ---- single-wave suffix scan: rcur[b] = sum_{b' > b} rh[b']  (start[b])
  if (t < 64) {
    const uint4 a = *(const uint4*)&rh[8 * t];
    const uint4 b = *(const uint4*)&rh[8 * t + 4];
    const uint32_t c0 = a.x, c1 = a.y, c2 = a.z, c3 = a.w;
    const uint32_t c4 = b.x, c5 = b.y, c6 = b.z, c7 = b.w;
    const uint32_t mysum = c0 + c1 + c2 + c3 + c4 + c5 + c6 + c7;
    uint32_t s = mysum;  // inclusive suffix over lanes
    for (int d = 1; d < 64; d <<= 1) {
      const uint32_t o = __shfl_down(s, d);
      if (t + d < 64) s += o;
    }
    uint32_t acc = s - mysum;  // sum over lanes > t
    rcur[8 * t + 7] = acc; acc += c7;
    rcur[8 * t + 6] = acc; acc += c6;
    rcur[8 * t + 5] = acc; acc += c5;
    rcur[8 * t + 4] = acc; acc += c4;
    rcur[8 * t + 3] = acc; acc += c3;
    rcur[8 * t + 2] = acc; acc += c2;
    rcur[8 * t + 1] = acc; acc += c1;
    rcur[8 * t + 0] = acc;
  }
  __syncthreads();

  // ---- scatter candidates into bin-ordered slots of buf2
  if ((uint32_t)t < cnt) {
    const uint32_t s = atomicAdd(&rcur[b0], 1u);
    buf2[s] = k0;
  }
  if ((uint32_t)(t + THREADS) < cnt) {
    const uint32_t s = atomicAdd(&rcur[b1], 1u);
    buf2[s] = k1;
  }
  __syncthreads();
  // now rcur[b] = start[b] + rh[b] = segment end for bin b

  const float s0 = (float)osz[0];
  const float s1 = (float)osz[1];

  if ((uint32_t)t < cnt)
    rank_emit(k0, b0, rcur, rh, buf2, boxes, out, n, s0, s1);
  if ((uint32_t)(t + THREADS) < cnt)
    rank_emit(k1, b1, rcur, rh, buf2, boxes, out, n, s0, s1);
}

extern "C" void kernel_launch(void* const* d_in, const int* in_sizes, int n_in,
                              void* d_out, int out_size, void* d_ws, size_t ws_size,
                              hipStream_t stream) {
  const float* logits = (const float*)d_in[0];
  const float* boxes = (const float*)d_in[1];
  const int* osz = (const int*)d_in[2];
  float* out = (float*)d_out;
  const int nbatch = in_sizes[0] / QK;  // 256
  detr_post_kernel<<<nbatch, THREADS, 0, stream>>>(logits, boxes, osz, out);
}